// Round 9
// baseline (316.532 us; speedup 1.0000x reference)
//
#include <hip/hip_runtime.h>
#include <math.h>

#define N_NODES 4096
#define N_EDGES 262144

typedef __attribute__((ext_vector_type(4))) float f32x4;
typedef __attribute__((ext_vector_type(8))) short s16x8;
typedef __attribute__((ext_vector_type(4))) unsigned short u16x4;

__device__ inline unsigned short f2bf(float f) {
    unsigned u = __builtin_bit_cast(unsigned, f);
    u += 0x7FFF + ((u >> 16) & 1);  // RNE
    return (unsigned short)(u >> 16);
}
__device__ inline unsigned short f2bf_t(float f) {  // truncate (1 op)
    return (unsigned short)(__builtin_bit_cast(unsigned, f) >> 16);
}
__device__ inline float bf2f(unsigned short u) {
    unsigned x = ((unsigned)u) << 16;
    return __builtin_bit_cast(float, x);
}

// T2 XOR swizzle for 128-byte LDS rows
#define SWZ(row, colb) (((row) << 7) + ((colb) ^ (((row) & 7) << 4)))

// ---------------------------------------------------------------------------
// Fused prep: x0->bf16, ipw(+K scale)->bf16, opw->bf16, W1/W2/W3 T->bf16, ipb,
// PLUS degree accumulation (deg/cnt pre-zeroed by hipMemsetAsync).
// ---------------------------------------------------------------------------
__global__ void prep_all(const float* __restrict__ x0, const float* __restrict__ ipw,
                         const float* __restrict__ opw, const float* __restrict__ ipb,
                         const float* __restrict__ W1, const float* __restrict__ W2,
                         const float* __restrict__ W3,
                         const int* __restrict__ col, const float* __restrict__ ew,
                         unsigned short* __restrict__ x0b, unsigned short* __restrict__ ipwb,
                         unsigned short* __restrict__ opwb, float* __restrict__ ipbs,
                         unsigned short* __restrict__ W1t, unsigned short* __restrict__ W2t,
                         unsigned short* __restrict__ W3t,
                         float* __restrict__ deg, int* __restrict__ cnt) {
    const int NA = 262144;   // x0 vec4
    const int NB = 49152;    // ipw vec4
    const int NC = 16384;    // opw vec4
    const int ND1 = 65536, ND2 = 65536, ND3 = 32768;  // transposes (scalar)
    const int NE = 768;
    const int NG = N_EDGES;  // degree accumulation
    const int total = NA + NB + NC + ND1 + ND2 + ND3 + NE + NG;
    for (int idx = blockIdx.x * blockDim.x + threadIdx.x; idx < total;
         idx += gridDim.x * blockDim.x) {
        int t = idx;
        if (t < NA) {
            int i = t * 4;
            f32x4 v = *(const f32x4*)(x0 + i);
            u16x4 o;
#pragma unroll
            for (int j = 0; j < 4; j++) o[j] = f2bf(v[j]);
            *(u16x4*)(x0b + i) = o;
            continue;
        }
        t -= NA;
        if (t < NB) {
            int i = t * 4;
            int r = i >> 8;
            float sc = (r >= 256 && r < 512) ? 0.1803369f : 1.0f;  // 0.125*log2(e)
            f32x4 v = *(const f32x4*)(ipw + i);
            u16x4 o;
#pragma unroll
            for (int j = 0; j < 4; j++) o[j] = f2bf(v[j] * sc);
            *(u16x4*)(ipwb + i) = o;
            continue;
        }
        t -= NB;
        if (t < NC) {
            int i = t * 4;
            f32x4 v = *(const f32x4*)(opw + i);
            u16x4 o;
#pragma unroll
            for (int j = 0; j < 4; j++) o[j] = f2bf(v[j]);
            *(u16x4*)(opwb + i) = o;
            continue;
        }
        t -= NC;
        if (t < ND1) {
            int r = t & 255, c = t >> 8;
            W1t[c * 256 + r] = f2bf(W1[r * 256 + c]);
            continue;
        }
        t -= ND1;
        if (t < ND2) {
            int r = t & 255, c = t >> 8;
            W2t[c * 256 + r] = f2bf(W2[r * 256 + c]);
            continue;
        }
        t -= ND2;
        if (t < ND3) {
            int r = t & 255, c = t >> 8;   // c in 0..127
            W3t[c * 256 + r] = f2bf(W3[r * 128 + c]);
            continue;
        }
        t -= ND3;
        if (t < NE) {
            float sc = (t >= 256 && t < 512) ? 0.1803369f : 1.0f;
            ipbs[t] = ipb[t] * sc;
            continue;
        }
        t -= NE;
        {
            int c = col[t];
            atomicAdd(&deg[c], ew[t]);
            atomicAdd(&cnt[c], 1);
        }
    }
}

// ---------------------------------------------------------------------------
// dinv = rsqrt(deg + 1) + exclusive scan of cnt
// ---------------------------------------------------------------------------
__global__ __launch_bounds__(1024) void scan_offsets(const int* __restrict__ cnt,
                                                     float* __restrict__ deg,
                                                     int* off, int* fill) {
    __shared__ int s[1024];
    int tid = threadIdx.x;
#pragma unroll
    for (int q = 0; q < 4; q++) {
        int i = tid * 4 + q;
        deg[i] = rsqrtf(deg[i] + 1.0f);
    }
    int c0 = cnt[tid * 4 + 0], c1 = cnt[tid * 4 + 1];
    int c2 = cnt[tid * 4 + 2], c3 = cnt[tid * 4 + 3];
    int lsum = c0 + c1 + c2 + c3;
    s[tid] = lsum;
    __syncthreads();
    for (int d = 1; d < 1024; d <<= 1) {
        int v = (tid >= d) ? s[tid - d] : 0;
        __syncthreads();
        s[tid] += v;
        __syncthreads();
    }
    int incl = s[tid];
    int base = incl - lsum;
    int o0 = base, o1 = base + c0, o2 = base + c0 + c1, o3 = base + c0 + c1 + c2;
    off[tid * 4 + 0] = o0;  fill[tid * 4 + 0] = o0;
    off[tid * 4 + 1] = o1;  fill[tid * 4 + 1] = o1;
    off[tid * 4 + 2] = o2;  fill[tid * 4 + 2] = o2;
    off[tid * 4 + 3] = o3;  fill[tid * 4 + 3] = o3;
    if (tid == 1023) off[4096] = incl;
}

// pack {row, norm} into one u64 per edge
__global__ void scatter_edges(const int* __restrict__ row, const int* __restrict__ col,
                              const float* __restrict__ ew, const float* __restrict__ dinv,
                              int* fill, unsigned long long* __restrict__ ep) {
    for (int e = blockIdx.x * blockDim.x + threadIdx.x; e < N_EDGES;
         e += gridDim.x * blockDim.x) {
        int r = row[e], c = col[e];
        int p = atomicAdd(&fill[c], 1);
        float w = dinv[r] * ew[e] * dinv[c];
        unsigned long long v =
            ((unsigned long long)__builtin_bit_cast(unsigned, w) << 32) | (unsigned)r;
        ep[p] = v;
    }
}

// ---------------------------------------------------------------------------
// Single-wave bf16 GEMM: 64x64 tile/wave (4 A-frags share 4 B-frags).
// C = A[N][256] @ B^T (B [P][256] bf16).
// QKV=true: bcol>=512 blocks write transposed Vt [head][d][n] directly.
// grid (P/64, N/64), 64 threads.
// ---------------------------------------------------------------------------
template <bool BIAS, int ACT, bool QKV>
__global__ __launch_bounds__(64) void gemm_bf16(const unsigned short* __restrict__ A,
                                                const unsigned short* __restrict__ B,
                                                const float* __restrict__ bias,
                                                unsigned short* __restrict__ C,
                                                unsigned short* __restrict__ Vt, int P) {
    int lane = threadIdx.x & 63;
    int lx = lane & 15, g = lane >> 4;
    int brow = blockIdx.y * 64, bcol = blockIdx.x * 64;
    const unsigned short* Ap = A + (size_t)(brow + lx) * 256 + g * 8;
    const unsigned short* Bp = B + (size_t)(bcol + lx) * 256 + g * 8;
    f32x4 acc[4][4];
#pragma unroll
    for (int mi = 0; mi < 4; mi++)
#pragma unroll
        for (int nt = 0; nt < 4; nt++) acc[mi][nt] = f32x4{0.f, 0.f, 0.f, 0.f};
#pragma unroll
    for (int kc = 0; kc < 8; kc++) {
        s16x8 a[4], b[4];
#pragma unroll
        for (int mi = 0; mi < 4; mi++)
            a[mi] = *(const s16x8*)(Ap + (size_t)mi * 16 * 256 + kc * 32);
#pragma unroll
        for (int nt = 0; nt < 4; nt++)
            b[nt] = *(const s16x8*)(Bp + (size_t)nt * 16 * 256 + kc * 32);
#pragma unroll
        for (int mi = 0; mi < 4; mi++)
#pragma unroll
            for (int nt = 0; nt < 4; nt++)
                acc[mi][nt] = __builtin_amdgcn_mfma_f32_16x16x32_bf16(a[mi], b[nt],
                                                                      acc[mi][nt], 0, 0, 0);
    }
    bool isV = QKV && (bcol >= 512);
    if (!isV) {
#pragma unroll
        for (int mi = 0; mi < 4; mi++)
#pragma unroll
            for (int nt = 0; nt < 4; nt++)
#pragma unroll
                for (int r = 0; r < 4; r++) {
                    int row = brow + mi * 16 + g * 4 + r, col = bcol + nt * 16 + lx;
                    float v = acc[mi][nt][r];
                    if (BIAS) v += bias[col];
                    if (ACT == 1) v = fmaxf(v, 0.f);
                    C[(size_t)row * P + col] = f2bf(v);
                }
    } else {
        int head = (bcol - 512) >> 6;
#pragma unroll
        for (int mi = 0; mi < 4; mi++)
#pragma unroll
            for (int nt = 0; nt < 4; nt++) {
                int col = bcol + nt * 16 + lx;
                u16x4 vv;
#pragma unroll
                for (int r = 0; r < 4; r++) {
                    float v = acc[mi][nt][r];
                    if (BIAS) v += bias[col];
                    vv[r] = f2bf(v);
                }
                *(u16x4*)(Vt + (size_t)(head * 64 + nt * 16 + lx) * 4096 +
                          brow + mi * 16 + g * 4) = vv;
            }
    }
}

// ---------------------------------------------------------------------------
// GCN aggregation: 4 waves per node. Waves take edges stride-4 interleaved
// (4x memory-level parallelism on the gather chain); LDS reduce at the end.
// ---------------------------------------------------------------------------
template <int P, bool SIG>
__global__ __launch_bounds__(256) void gcn_agg(const unsigned short* __restrict__ H,
                                               const int* __restrict__ off,
                                               const unsigned long long* __restrict__ ep,
                                               const float* __restrict__ dinv,
                                               const float* __restrict__ bias,
                                               unsigned short* __restrict__ outb,
                                               float* __restrict__ outf) {
    constexpr int CPT = P / 64;  // cols per lane (4 or 2)
    __shared__ unsigned long long se[128];
    __shared__ float red[3][P];
    int i = blockIdx.x, tid = threadIdx.x;
    int wid = tid >> 6, lane = tid & 63;
    float acc[CPT];
#pragma unroll
    for (int j = 0; j < CPT; j++) acc[j] = 0.f;
    if (wid == 0) {
        float di = dinv[i];
        float d2 = di * di;
        if (CPT == 4) {
            u16x4 h = *(const u16x4*)(H + (size_t)i * P + lane * 4);
#pragma unroll
            for (int j = 0; j < 4; j++) acc[j] = d2 * bf2f(h[j]);
        } else {
            unsigned h = *(const unsigned*)(H + (size_t)i * P + lane * 2);
            acc[0] = d2 * bf2f((unsigned short)(h & 0xFFFF));
            acc[1] = d2 * bf2f((unsigned short)(h >> 16));
        }
    }
    int beg = off[i], end = off[i + 1];
    for (int base = beg; base < end; base += 128) {
        int n = min(128, end - base);
        __syncthreads();
        if (tid < n) se[tid] = ep[base + tid];
        __syncthreads();
        for (int j = wid; j < n; j += 4) {
            unsigned long long v = se[j];
            int r = (int)(unsigned)v;
            float w = __builtin_bit_cast(float, (unsigned)(v >> 32));
            size_t rb = (size_t)r * P;
            if (CPT == 4) {
                u16x4 h = *(const u16x4*)(H + rb + lane * 4);
#pragma unroll
                for (int q = 0; q < 4; q++) acc[q] += w * bf2f(h[q]);
            } else {
                unsigned h = *(const unsigned*)(H + rb + lane * 2);
                acc[0] += w * bf2f((unsigned short)(h & 0xFFFF));
                acc[1] += w * bf2f((unsigned short)(h >> 16));
            }
        }
    }
    if (wid > 0) {
#pragma unroll
        for (int j = 0; j < CPT; j++) red[wid - 1][lane * CPT + j] = acc[j];
    }
    __syncthreads();
    if (wid == 0) {
#pragma unroll
        for (int j = 0; j < CPT; j++) {
            int c = lane * CPT + j;
            float v = acc[j] + red[0][c] + red[1][c] + red[2][c] + bias[c];
            if (SIG) {
                v = 1.f / (1.f + exp2f(-v * 1.442695f));
                outf[(size_t)i * P + c] = v;
            } else {
                outb[(size_t)i * P + c] = f2bf(v);
            }
        }
    }
}

// ---------------------------------------------------------------------------
// MFMA flash attention (round-7 version): fixed-base exp2 softmax,
// double-buffered K/V, 4 KV chunks, 16 q-rows/wave, 40 KB LDS.
// grid (64 q-tiles, 4 heads, 4 chunks), 256 threads = 4 waves.
// ---------------------------------------------------------------------------
__global__ __launch_bounds__(256) void attn_mfma(const unsigned short* __restrict__ qkv,
                                                 const unsigned short* __restrict__ Vt,
                                                 unsigned short* __restrict__ Po,
                                                 float* __restrict__ Pl) {
    __shared__ unsigned short Ks[2][64 * 64];
    __shared__ unsigned short Vs[2][64 * 64];
    __shared__ unsigned short Ps[4][16 * 64];

    int tid = threadIdx.x;
    int wid = tid >> 6, lane = tid & 63, g = lane >> 4, lx = lane & 15;
    int head = blockIdx.y, chunk = blockIdx.z;
    int qw = blockIdx.x * 64 + wid * 16;

    s16x8 qa[2];
#pragma unroll
    for (int kc = 0; kc < 2; kc++)
        qa[kc] = *(const s16x8*)(qkv + (size_t)(qw + lx) * 768 + head * 64 + kc * 32 + g * 8);

    int kr0 = tid >> 3, dc0 = tid & 7;
    int kr1 = kr0 + 32;
    int kt_beg = chunk * 16, kt_end = kt_beg + 16;

    const unsigned short* kp0 =
        qkv + 256 + head * 64 + (size_t)(kt_beg * 64 + kr0) * 768 + dc0 * 8;
    const unsigned short* kp1 = kp0 + (size_t)32 * 768;
    const unsigned short* vp0 =
        Vt + (size_t)head * 64 * 4096 + (size_t)kr0 * 4096 + kt_beg * 64 + dc0 * 8;
    const unsigned short* vp1 = vp0 + (size_t)32 * 4096;

    s16x8 stK[2], stV[2];
    auto issue = [&]() {
        stK[0] = *(const s16x8*)kp0;
        stK[1] = *(const s16x8*)kp1;
        stV[0] = *(const s16x8*)vp0;
        stV[1] = *(const s16x8*)vp1;
        kp0 += 64 * 768; kp1 += 64 * 768;
        vp0 += 64; vp1 += 64;
    };
    auto commit = [&](int b) {
        *(s16x8*)((char*)Ks[b] + SWZ(kr0, dc0 * 16)) = stK[0];
        *(s16x8*)((char*)Ks[b] + SWZ(kr1, dc0 * 16)) = stK[1];
        *(s16x8*)((char*)Vs[b] + SWZ(kr0, dc0 * 16)) = stV[0];
        *(s16x8*)((char*)Vs[b] + SWZ(kr1, dc0 * 16)) = stV[1];
    };

    float lreg[4] = {0.f, 0.f, 0.f, 0.f};
    f32x4 o[4];
#pragma unroll
    for (int dt = 0; dt < 4; dt++) o[dt] = f32x4{0.f, 0.f, 0.f, 0.f};

    char* PsW = (char*)Ps[wid];

    issue();
    commit(0);
    __syncthreads();

    for (int kt = kt_beg; kt < kt_end; kt++) {
        int cur = (kt - kt_beg) & 1;
        if (kt + 1 < kt_end) issue();

        f32x4 s4[4];
        __builtin_amdgcn_s_setprio(1);
#pragma unroll
        for (int nt = 0; nt < 4; nt++) {
            f32x4 acc = f32x4{0.f, 0.f, 0.f, 0.f};
#pragma unroll
            for (int kc = 0; kc < 2; kc++) {
                s16x8 kb = *(const s16x8*)((char*)Ks[cur] + SWZ(nt * 16 + lx, kc * 64 + g * 16));
                acc = __builtin_amdgcn_mfma_f32_16x16x32_bf16(qa[kc], kb, acc, 0, 0, 0);
            }
            s4[nt] = acc;
        }
        __builtin_amdgcn_s_setprio(0);

        // fixed-base softmax: P = exp2(min(s,60)); per-lane l accumulation
#pragma unroll
        for (int nt = 0; nt < 4; nt++)
#pragma unroll
            for (int r = 0; r < 4; r++) {
                float p = exp2f(fminf(s4[nt][r], 60.f));
                lreg[r] += p;
                *(unsigned short*)(PsW + SWZ(4 * g + r, (nt * 16 + lx) * 2)) = f2bf_t(p);
            }

        __builtin_amdgcn_s_setprio(1);
#pragma unroll
        for (int kc = 0; kc < 2; kc++) {
            s16x8 pa = *(const s16x8*)(PsW + SWZ(lx, kc * 64 + g * 16));
#pragma unroll
            for (int dt = 0; dt < 4; dt++) {
                s16x8 vb = *(const s16x8*)((char*)Vs[cur] + SWZ(dt * 16 + lx, kc * 64 + g * 16));
                o[dt] = __builtin_amdgcn_mfma_f32_16x16x32_bf16(pa, vb, o[dt], 0, 0, 0);
            }
        }
        __builtin_amdgcn_s_setprio(0);

        if (kt + 1 < kt_end) commit(1 - cur);
        __syncthreads();
    }

#pragma unroll
    for (int r = 0; r < 4; r++) {
        float ls = lreg[r];
        ls += __shfl_xor(ls, 1, 16);
        ls += __shfl_xor(ls, 2, 16);
        ls += __shfl_xor(ls, 4, 16);
        ls += __shfl_xor(ls, 8, 16);
        int qrow = qw + 4 * g + r;
        size_t base = (size_t)(chunk * 4 + head) * 4096 + qrow;
        if (lx == 0) Pl[base] = ls;
#pragma unroll
        for (int dt = 0; dt < 4; dt++)
            Po[base * 64 + dt * 16 + lx] = f2bf(o[dt][r]);
    }
}

// ---------------------------------------------------------------------------
// Combine 4 chunk-partials -> att bf16 [N][256]. 4 q-rows per block.
// ---------------------------------------------------------------------------
__global__ __launch_bounds__(256) void attn_combine(const unsigned short* __restrict__ Po,
                                                    const float* __restrict__ Pl,
                                                    unsigned short* __restrict__ att) {
    int tid = threadIdx.x;
    int q = blockIdx.x * 4 + (tid >> 6);
    int lane = tid & 63;
    int head = lane >> 4, quad = lane & 15;
    float L = 0.f;
    f32x4 ov = {0.f, 0.f, 0.f, 0.f};
#pragma unroll
    for (int c = 0; c < 4; c++) {
        size_t base = (size_t)(c * 4 + head) * 4096 + q;
        L += Pl[base];
        u16x4 p = *(const u16x4*)(Po + base * 64 + quad * 4);
#pragma unroll
        for (int k = 0; k < 4; k++) ov[k] += bf2f(p[k]);
    }
    float inv = 1.0f / L;
    u16x4 r;
#pragma unroll
    for (int k = 0; k < 4; k++) r[k] = f2bf(ov[k] * inv);
    *(u16x4*)(att + (size_t)q * 256 + head * 64 + quad * 4) = r;
}

// ---------------------------------------------------------------------------
extern "C" void kernel_launch(void* const* d_in, const int* in_sizes, int n_in,
                              void* d_out, int out_size, void* d_ws, size_t ws_size,
                              hipStream_t stream) {
    const float* x0  = (const float*)d_in[0];
    const int*   eix = (const int*)d_in[1];
    const float* ew  = (const float*)d_in[2];
    const float* W1  = (const float*)d_in[3];
    const float* b1  = (const float*)d_in[4];
    const float* W2  = (const float*)d_in[5];
    const float* b2  = (const float*)d_in[6];
    const float* W3  = (const float*)d_in[7];
    const float* b3  = (const float*)d_in[8];
    const float* ipw = (const float*)d_in[9];
    const float* ipb = (const float*)d_in[10];
    const float* opw = (const float*)d_in[11];
    const float* opb = (const float*)d_in[12];
    float* out = (float*)d_out;

    char* ws = (char*)d_ws;
    size_t o = 0;
    auto alloc = [&](size_t bytes) -> void* {
        void* p = ws + o;
        o = (o + bytes + 255) & ~size_t(255);
        return p;
    };
    float* dinv  = (float*)alloc(N_NODES * 4);   // deg -> dinv in place
    int*   cnt   = (int*)alloc(N_NODES * 4);
    int*   off   = (int*)alloc((N_NODES + 1) * 4);
    int*   fill  = (int*)alloc(N_NODES * 4);
    unsigned long long* ep = (unsigned long long*)alloc((size_t)N_EDGES * 8);
    unsigned short* x0b  = (unsigned short*)alloc((size_t)N_NODES * 256 * 2);
    unsigned short* W1t  = (unsigned short*)alloc(256 * 256 * 2);
    unsigned short* W2t  = (unsigned short*)alloc(256 * 256 * 2);
    unsigned short* W3t  = (unsigned short*)alloc(128 * 256 * 2);
    unsigned short* ipwb = (unsigned short*)alloc(768 * 256 * 2);
    unsigned short* opwb = (unsigned short*)alloc(256 * 256 * 2);
    float* ipbs          = (float*)alloc(768 * 4);
    unsigned short* Hb   = (unsigned short*)alloc((size_t)N_NODES * 256 * 2);
    unsigned short* XAb  = (unsigned short*)alloc((size_t)N_NODES * 256 * 2);
    unsigned short* XBb  = (unsigned short*)alloc((size_t)N_NODES * 256 * 2);
    unsigned short* QKVb = (unsigned short*)alloc((size_t)N_NODES * 768 * 2);
    unsigned short* Vt   = (unsigned short*)alloc((size_t)4 * 64 * 4096 * 2);
    unsigned short* Po   = (unsigned short*)alloc((size_t)16 * 4096 * 64 * 2);
    float* Pl            = (float*)alloc((size_t)16 * 4096 * 4);

    const int* row = eix;
    const int* col = eix + N_EDGES;

    hipMemsetAsync(dinv, 0, N_NODES * 4, stream);
    hipMemsetAsync(cnt, 0, N_NODES * 4, stream);
    prep_all<<<512, 256, 0, stream>>>(x0, ipw, opw, ipb, W1, W2, W3, col, ew,
                                      x0b, ipwb, opwb, ipbs, W1t, W2t, W3t, dinv, cnt);
    scan_offsets<<<1, 1024, 0, stream>>>(cnt, dinv, off, fill);
    scatter_edges<<<512, 256, 0, stream>>>(row, col, ew, dinv, fill, ep);

    // GCN layer 1
    gemm_bf16<false, 0, false><<<dim3(4, 64), 64, 0, stream>>>(x0b, W1t, nullptr, Hb, nullptr, 256);
    gcn_agg<256, false><<<N_NODES, 256, 0, stream>>>(Hb, off, ep, dinv, b1, XAb, nullptr);
    // MHA 1 (+relu)
    gemm_bf16<true, 0, true><<<dim3(12, 64), 64, 0, stream>>>(XAb, ipwb, ipbs, QKVb, Vt, 768);
    attn_mfma<<<dim3(64, 4, 4), 256, 0, stream>>>(QKVb, Vt, Po, Pl);
    attn_combine<<<N_NODES / 4, 256, 0, stream>>>(Po, Pl, Hb);
    gemm_bf16<true, 1, false><<<dim3(4, 64), 64, 0, stream>>>(Hb, opwb, opb, XBb, nullptr, 256);
    // GCN layer 2
    gemm_bf16<false, 0, false><<<dim3(4, 64), 64, 0, stream>>>(XBb, W2t, nullptr, Hb, nullptr, 256);
    gcn_agg<256, false><<<N_NODES, 256, 0, stream>>>(Hb, off, ep, dinv, b2, XAb, nullptr);
    // MHA 2 (+relu)
    gemm_bf16<true, 0, true><<<dim3(12, 64), 64, 0, stream>>>(XAb, ipwb, ipbs, QKVb, Vt, 768);
    attn_mfma<<<dim3(64, 4, 4), 256, 0, stream>>>(QKVb, Vt, Po, Pl);
    attn_combine<<<N_NODES / 4, 256, 0, stream>>>(Po, Pl, Hb);
    gemm_bf16<true, 1, false><<<dim3(4, 64), 64, 0, stream>>>(Hb, opwb, opb, XBb, nullptr, 256);
    // GCN layer 3 (+sigmoid) -> d_out
    gemm_bf16<false, 0, false><<<dim3(2, 64), 64, 0, stream>>>(XBb, W3t, nullptr, Hb, nullptr, 128);
    gcn_agg<128, true><<<N_NODES, 256, 0, stream>>>(Hb, off, ep, dinv, b3, nullptr, out);
}

// Round 11
// 302.857 us; speedup vs baseline: 1.0452x; 1.0452x over previous
//
#include <hip/hip_runtime.h>
#include <math.h>

#define N_NODES 4096
#define N_EDGES 262144

typedef __attribute__((ext_vector_type(4))) float f32x4;
typedef __attribute__((ext_vector_type(8))) short s16x8;
typedef __attribute__((ext_vector_type(4))) unsigned short u16x4;

__device__ inline unsigned short f2bf(float f) {
    unsigned u = __builtin_bit_cast(unsigned, f);
    u += 0x7FFF + ((u >> 16) & 1);  // RNE
    return (unsigned short)(u >> 16);
}
__device__ inline unsigned short f2bf_t(float f) {  // truncate (1 op)
    return (unsigned short)(__builtin_bit_cast(unsigned, f) >> 16);
}
__device__ inline float bf2f(unsigned short u) {
    unsigned x = ((unsigned)u) << 16;
    return __builtin_bit_cast(float, x);
}

// T2 XOR swizzle for 128-byte LDS rows
#define SWZ(row, colb) (((row) << 7) + ((colb) ^ (((row) & 7) << 4)))

// ---------------------------------------------------------------------------
// Fused prep: x0->bf16, ipw(+K scale)->bf16, opw->bf16, W1/W2/W3 T->bf16, ipb
// ---------------------------------------------------------------------------
__global__ void prep_all(const float* __restrict__ x0, const float* __restrict__ ipw,
                         const float* __restrict__ opw, const float* __restrict__ ipb,
                         const float* __restrict__ W1, const float* __restrict__ W2,
                         const float* __restrict__ W3,
                         unsigned short* __restrict__ x0b, unsigned short* __restrict__ ipwb,
                         unsigned short* __restrict__ opwb, float* __restrict__ ipbs,
                         unsigned short* __restrict__ W1t, unsigned short* __restrict__ W2t,
                         unsigned short* __restrict__ W3t) {
    const int NA = 262144;   // x0 vec4
    const int NB = 49152;    // ipw vec4
    const int NC = 16384;    // opw vec4
    const int ND1 = 65536, ND2 = 65536, ND3 = 32768;  // transposes (scalar)
    const int NE = 768;
    const int total = NA + NB + NC + ND1 + ND2 + ND3 + NE;
    for (int idx = blockIdx.x * blockDim.x + threadIdx.x; idx < total;
         idx += gridDim.x * blockDim.x) {
        int t = idx;
        if (t < NA) {
            int i = t * 4;
            f32x4 v = *(const f32x4*)(x0 + i);
            u16x4 o;
#pragma unroll
            for (int j = 0; j < 4; j++) o[j] = f2bf(v[j]);
            *(u16x4*)(x0b + i) = o;
            continue;
        }
        t -= NA;
        if (t < NB) {
            int i = t * 4;
            int r = i >> 8;
            float sc = (r >= 256 && r < 512) ? 0.1803369f : 1.0f;  // 0.125*log2(e)
            f32x4 v = *(const f32x4*)(ipw + i);
            u16x4 o;
#pragma unroll
            for (int j = 0; j < 4; j++) o[j] = f2bf(v[j] * sc);
            *(u16x4*)(ipwb + i) = o;
            continue;
        }
        t -= NB;
        if (t < NC) {
            int i = t * 4;
            f32x4 v = *(const f32x4*)(opw + i);
            u16x4 o;
#pragma unroll
            for (int j = 0; j < 4; j++) o[j] = f2bf(v[j]);
            *(u16x4*)(opwb + i) = o;
            continue;
        }
        t -= NC;
        if (t < ND1) {
            int r = t & 255, c = t >> 8;
            W1t[c * 256 + r] = f2bf(W1[r * 256 + c]);
            continue;
        }
        t -= ND1;
        if (t < ND2) {
            int r = t & 255, c = t >> 8;
            W2t[c * 256 + r] = f2bf(W2[r * 256 + c]);
            continue;
        }
        t -= ND2;
        if (t < ND3) {
            int r = t & 255, c = t >> 8;   // c in 0..127
            W3t[c * 256 + r] = f2bf(W3[r * 128 + c]);
            continue;
        }
        t -= ND3;
        {
            float sc = (t >= 256 && t < 512) ? 0.1803369f : 1.0f;
            ipbs[t] = ipb[t] * sc;
        }
    }
}

// ---------------------------------------------------------------------------
// Graph preprocessing (deg/cnt zeroed by hipMemsetAsync)
// ---------------------------------------------------------------------------
__global__ void deg_accum(const int* __restrict__ col, const float* __restrict__ ew,
                          float* deg, int* cnt) {
    for (int e = blockIdx.x * blockDim.x + threadIdx.x; e < N_EDGES;
         e += gridDim.x * blockDim.x) {
        int c = col[e];
        atomicAdd(&deg[c], ew[e]);
        atomicAdd(&cnt[c], 1);
    }
}

// dinv = rsqrt(deg + 1) + exclusive scan of cnt
__global__ __launch_bounds__(1024) void scan_offsets(const int* __restrict__ cnt,
                                                     float* __restrict__ deg,
                                                     int* off, int* fill) {
    __shared__ int s[1024];
    int tid = threadIdx.x;
#pragma unroll
    for (int q = 0; q < 4; q++) {
        int i = tid * 4 + q;
        deg[i] = rsqrtf(deg[i] + 1.0f);
    }
    int c0 = cnt[tid * 4 + 0], c1 = cnt[tid * 4 + 1];
    int c2 = cnt[tid * 4 + 2], c3 = cnt[tid * 4 + 3];
    int lsum = c0 + c1 + c2 + c3;
    s[tid] = lsum;
    __syncthreads();
    for (int d = 1; d < 1024; d <<= 1) {
        int v = (tid >= d) ? s[tid - d] : 0;
        __syncthreads();
        s[tid] += v;
        __syncthreads();
    }
    int incl = s[tid];
    int base = incl - lsum;
    int o0 = base, o1 = base + c0, o2 = base + c0 + c1, o3 = base + c0 + c1 + c2;
    off[tid * 4 + 0] = o0;  fill[tid * 4 + 0] = o0;
    off[tid * 4 + 1] = o1;  fill[tid * 4 + 1] = o1;
    off[tid * 4 + 2] = o2;  fill[tid * 4 + 2] = o2;
    off[tid * 4 + 3] = o3;  fill[tid * 4 + 3] = o3;
    if (tid == 1023) off[4096] = incl;
}

// pack {row, norm} into one u64 per edge
__global__ void scatter_edges(const int* __restrict__ row, const int* __restrict__ col,
                              const float* __restrict__ ew, const float* __restrict__ dinv,
                              int* fill, unsigned long long* __restrict__ ep) {
    for (int e = blockIdx.x * blockDim.x + threadIdx.x; e < N_EDGES;
         e += gridDim.x * blockDim.x) {
        int r = row[e], c = col[e];
        int p = atomicAdd(&fill[c], 1);
        float w = dinv[r] * ew[e] * dinv[c];
        unsigned long long v =
            ((unsigned long long)__builtin_bit_cast(unsigned, w) << 32) | (unsigned)r;
        ep[p] = v;
    }
}

// ---------------------------------------------------------------------------
// Single-wave bf16 GEMM: 32x64 tile/wave. C = A[N][256] @ B^T (B [P][256] bf16)
// QKV=true: bcol>=512 blocks write transposed Vt [head][d][n] directly.
// grid (P/64, N/32), 64 threads.
// ---------------------------------------------------------------------------
template <bool BIAS, int ACT, bool QKV>
__global__ __launch_bounds__(64) void gemm_bf16(const unsigned short* __restrict__ A,
                                                const unsigned short* __restrict__ B,
                                                const float* __restrict__ bias,
                                                unsigned short* __restrict__ C,
                                                unsigned short* __restrict__ Vt, int P) {
    int lane = threadIdx.x & 63;
    int lx = lane & 15, g = lane >> 4;
    int brow = blockIdx.y * 32, bcol = blockIdx.x * 64;
    const unsigned short* Ap0 = A + (size_t)(brow + lx) * 256 + g * 8;
    const unsigned short* Ap1 = Ap0 + 16 * 256;
    const unsigned short* Bp = B + (size_t)(bcol + lx) * 256 + g * 8;
    f32x4 acc[2][4];
#pragma unroll
    for (int mi = 0; mi < 2; mi++)
#pragma unroll
        for (int nt = 0; nt < 4; nt++) acc[mi][nt] = f32x4{0.f, 0.f, 0.f, 0.f};
#pragma unroll
    for (int kc = 0; kc < 8; kc++) {
        s16x8 a0 = *(const s16x8*)(Ap0 + kc * 32);
        s16x8 a1 = *(const s16x8*)(Ap1 + kc * 32);
#pragma unroll
        for (int nt = 0; nt < 4; nt++) {
            s16x8 b = *(const s16x8*)(Bp + (size_t)nt * 16 * 256 + kc * 32);
            acc[0][nt] = __builtin_amdgcn_mfma_f32_16x16x32_bf16(a0, b, acc[0][nt], 0, 0, 0);
            acc[1][nt] = __builtin_amdgcn_mfma_f32_16x16x32_bf16(a1, b, acc[1][nt], 0, 0, 0);
        }
    }
    bool isV = QKV && (bcol >= 512);
    if (!isV) {
#pragma unroll
        for (int mi = 0; mi < 2; mi++)
#pragma unroll
            for (int nt = 0; nt < 4; nt++)
#pragma unroll
                for (int r = 0; r < 4; r++) {
                    int row = brow + mi * 16 + g * 4 + r, col = bcol + nt * 16 + lx;
                    float v = acc[mi][nt][r];
                    if (BIAS) v += bias[col];
                    if (ACT == 1) v = fmaxf(v, 0.f);
                    C[(size_t)row * P + col] = f2bf(v);
                }
    } else {
        int head = (bcol - 512) >> 6;
#pragma unroll
        for (int mi = 0; mi < 2; mi++)
#pragma unroll
            for (int nt = 0; nt < 4; nt++) {
                int col = bcol + nt * 16 + lx;
                u16x4 vv;
#pragma unroll
                for (int r = 0; r < 4; r++) {
                    float v = acc[mi][nt][r];
                    if (BIAS) v += bias[col];
                    vv[r] = f2bf(v);
                }
                *(u16x4*)(Vt + (size_t)(head * 64 + nt * 16 + lx) * 4096 +
                          brow + mi * 16 + g * 4) = vv;
            }
    }
}

// ---------------------------------------------------------------------------
// GCN aggregation: 1 wave per node, packed edge metadata, 128-edge LDS stages
// ---------------------------------------------------------------------------
template <int P, bool SIG>
__global__ __launch_bounds__(64) void gcn_agg(const unsigned short* __restrict__ H,
                                              const int* __restrict__ off,
                                              const unsigned long long* __restrict__ ep,
                                              const float* __restrict__ dinv,
                                              const float* __restrict__ bias,
                                              unsigned short* __restrict__ outb,
                                              float* __restrict__ outf) {
    constexpr int CPT = P / 64;  // cols per thread (4 or 2)
    __shared__ unsigned long long se[128];
    int i = blockIdx.x, tid = threadIdx.x;
    float di = dinv[i];
    float d2 = di * di;
    float acc[CPT];
    if (CPT == 4) {
        u16x4 h = *(const u16x4*)(H + (size_t)i * P + tid * 4);
#pragma unroll
        for (int j = 0; j < 4; j++) acc[j] = d2 * bf2f(h[j]);
    } else {
        unsigned h = *(const unsigned*)(H + (size_t)i * P + tid * 2);
        acc[0] = d2 * bf2f((unsigned short)(h & 0xFFFF));
        acc[1] = d2 * bf2f((unsigned short)(h >> 16));
    }
    int beg = off[i], end = off[i + 1];
    for (int base = beg; base < end; base += 128) {
        int n = min(128, end - base);
        __syncthreads();
        if (tid < n) se[tid] = ep[base + tid];
        if (tid + 64 < n) se[tid + 64] = ep[base + tid + 64];
        __syncthreads();
#pragma unroll 4
        for (int j = 0; j < n; j++) {
            unsigned long long v = se[j];
            int r = (int)(unsigned)v;
            float w = __builtin_bit_cast(float, (unsigned)(v >> 32));
            size_t rb = (size_t)r * P;
            if (CPT == 4) {
                u16x4 h = *(const u16x4*)(H + rb + tid * 4);
#pragma unroll
                for (int q = 0; q < 4; q++) acc[q] += w * bf2f(h[q]);
            } else {
                unsigned h = *(const unsigned*)(H + rb + tid * 2);
                acc[0] += w * bf2f((unsigned short)(h & 0xFFFF));
                acc[1] += w * bf2f((unsigned short)(h >> 16));
            }
        }
    }
#pragma unroll
    for (int j = 0; j < CPT; j++) {
        int c = tid * CPT + j;
        float v = acc[j] + bias[c];
        if (SIG) {
            v = 1.f / (1.f + exp2f(-v * 1.442695f));
            outf[(size_t)i * P + c] = v;
        } else {
            outb[(size_t)i * P + c] = f2bf(v);
        }
    }
}

// ---------------------------------------------------------------------------
// MFMA flash attention: fixed-base exp2 softmax, double-buffered K/V LDS,
// 2-deep register prefetch, XCD-pinned (head,chunk) block decode.
// grid 1024 blocks 1D; 256 threads = 4 waves x 16 q-rows. 40 KB LDS.
// ---------------------------------------------------------------------------
struct Stage { s16x8 K0, K1, V0, V1; };

__global__ __launch_bounds__(256) void attn_mfma(const unsigned short* __restrict__ qkv,
                                                 const unsigned short* __restrict__ Vt,
                                                 unsigned short* __restrict__ Po,
                                                 float* __restrict__ Pl) {
    __shared__ unsigned short Ks[2][64 * 64];
    __shared__ unsigned short Vs[2][64 * 64];
    __shared__ unsigned short Ps[4][16 * 64];

    int tid = threadIdx.x;
    int wid = tid >> 6, lane = tid & 63, g = lane >> 4, lx = lane & 15;
    // XCD-pinned decode (assumes XCD = dispatch index % 8): each XCD owns
    // 2 (head,chunk) pairs x 64 q-tiles -> K/V slice stays in its L2.
    int bid = blockIdx.x;
    int xcd = bid & 7, loc = bid >> 3;
    int pair = xcd * 2 + (loc >> 6);
    int qt = loc & 63;
    int head = pair >> 2, chunk = pair & 3;
    int qw = qt * 64 + wid * 16;

    s16x8 qa[2];
#pragma unroll
    for (int kc = 0; kc < 2; kc++)
        qa[kc] = *(const s16x8*)(qkv + (size_t)(qw + lx) * 768 + head * 64 + kc * 32 + g * 8);

    int kr0 = tid >> 3, dc0 = tid & 7;
    int kr1 = kr0 + 32;
    int kt_beg = chunk * 16;

    const unsigned short* kp0 =
        qkv + 256 + head * 64 + (size_t)(kt_beg * 64 + kr0) * 768 + dc0 * 8;
    const unsigned short* kp1 = kp0 + (size_t)32 * 768;
    const unsigned short* vp0 =
        Vt + (size_t)head * 64 * 4096 + (size_t)kr0 * 4096 + kt_beg * 64 + dc0 * 8;
    const unsigned short* vp1 = vp0 + (size_t)32 * 4096;

    Stage sA, sB;
    auto issue = [&](Stage& S) {
        S.K0 = *(const s16x8*)kp0;
        S.K1 = *(const s16x8*)kp1;
        S.V0 = *(const s16x8*)vp0;
        S.V1 = *(const s16x8*)vp1;
        kp0 += (size_t)64 * 768; kp1 += (size_t)64 * 768;
        vp0 += 64; vp1 += 64;
    };
    auto commit = [&](const Stage& S, int b) {
        *(s16x8*)((char*)Ks[b] + SWZ(kr0, dc0 * 16)) = S.K0;
        *(s16x8*)((char*)Ks[b] + SWZ(kr1, dc0 * 16)) = S.K1;
        *(s16x8*)((char*)Vs[b] + SWZ(kr0, dc0 * 16)) = S.V0;
        *(s16x8*)((char*)Vs[b] + SWZ(kr1, dc0 * 16)) = S.V1;
    };

    float lreg[4] = {0.f, 0.f, 0.f, 0.f};
    f32x4 o[4];
#pragma unroll
    for (int dt = 0; dt < 4; dt++) o[dt] = f32x4{0.f, 0.f, 0.f, 0.f};

    char* PsW = (char*)Ps[wid];

    auto compute = [&](int cur) {
        f32x4 s4[4];
        __builtin_amdgcn_s_setprio(1);
#pragma unroll
        for (int nt = 0; nt < 4; nt++) {
            f32x4 acc = f32x4{0.f, 0.f, 0.f, 0.f};
#pragma unroll
            for (int kc = 0; kc < 2; kc++) {
                s16x8 kb = *(const s16x8*)((char*)Ks[cur] + SWZ(nt * 16 + lx, kc * 64 + g * 16));
                acc = __builtin_amdgcn_mfma_f32_16x16x32_bf16(qa[kc], kb, acc, 0, 0, 0);
            }
            s4[nt] = acc;
        }
        __builtin_amdgcn_s_setprio(0);

        // fixed-base softmax: P = exp2(min(s,60)); per-lane l accumulation
#pragma unroll
        for (int nt = 0; nt < 4; nt++)
#pragma unroll
            for (int r = 0; r < 4; r++) {
                float p = exp2f(fminf(s4[nt][r], 60.f));
                lreg[r] += p;
                *(unsigned short*)(PsW + SWZ(4 * g + r, (nt * 16 + lx) * 2)) = f2bf_t(p);
            }

        __builtin_amdgcn_s_setprio(1);
#pragma unroll
        for (int kc = 0; kc < 2; kc++) {
            s16x8 pa = *(const s16x8*)(PsW + SWZ(lx, kc * 64 + g * 16));
#pragma unroll
            for (int dt = 0; dt < 4; dt++) {
                s16x8 vb = *(const s16x8*)((char*)Vs[cur] + SWZ(dt * 16 + lx, kc * 64 + g * 16));
                o[dt] = __builtin_amdgcn_mfma_f32_16x16x32_bf16(pa, vb, o[dt], 0, 0, 0);
            }
        }
        __builtin_amdgcn_s_setprio(0);
    };

    // prologue: t0 -> buf0 (serial), t1 in flight in sB
    issue(sA);
    commit(sA, 0);
    issue(sB);
    __syncthreads();

    // steady state: 2 tiles per iteration, 2-deep prefetch
    for (int it = 0; it < 16; it += 2) {
        if (it + 2 < 16) issue(sA);      // t_{it+2}
        compute(0);                      // tile it (buf0)
        commit(sB, 1);                   // t_{it+1} -> buf1
        __syncthreads();
        if (it + 3 < 16) issue(sB);      // t_{it+3}
        compute(1);                      // tile it+1 (buf1)
        if (it + 2 < 16) commit(sA, 0);  // t_{it+2} -> buf0
        __syncthreads();
    }

#pragma unroll
    for (int r = 0; r < 4; r++) {
        float ls = lreg[r];
        ls += __shfl_xor(ls, 1, 16);
        ls += __shfl_xor(ls, 2, 16);
        ls += __shfl_xor(ls, 4, 16);
        ls += __shfl_xor(ls, 8, 16);
        int qrow = qw + 4 * g + r;
        size_t base = (size_t)(chunk * 4 + head) * 4096 + qrow;
        if (lx == 0) Pl[base] = ls;
#pragma unroll
        for (int dt = 0; dt < 4; dt++)
            Po[base * 64 + dt * 16 + lx] = f2bf(o[dt][r]);
    }
}

// ---------------------------------------------------------------------------
// Combine 4 chunk-partials -> att bf16 [N][256]. 4 q-rows per block.
// ---------------------------------------------------------------------------
__global__ __launch_bounds__(256) void attn_combine(const unsigned short* __restrict__ Po,
                                                    const float* __restrict__ Pl,
                                                    unsigned short* __restrict__ att) {
    int tid = threadIdx.x;
    int q = blockIdx.x * 4 + (tid >> 6);
    int lane = tid & 63;
    int head = lane >> 4, quad = lane & 15;
    float L = 0.f;
    f32x4 ov = {0.f, 0.f, 0.f, 0.f};
#pragma unroll
    for (int c = 0; c < 4; c++) {
        size_t base = (size_t)(c * 4 + head) * 4096 + q;
        L += Pl[base];
        u16x4 p = *(const u16x4*)(Po + base * 64 + quad * 4);
#pragma unroll
        for (int k = 0; k < 4; k++) ov[k] += bf2f(p[k]);
    }
    float inv = 1.0f / L;
    u16x4 r;
#pragma unroll
    for (int k = 0; k < 4; k++) r[k] = f2bf(ov[k] * inv);
    *(u16x4*)(att + (size_t)q * 256 + head * 64 + quad * 4) = r;
}

// ---------------------------------------------------------------------------
extern "C" void kernel_launch(void* const* d_in, const int* in_sizes, int n_in,
                              void* d_out, int out_size, void* d_ws, size_t ws_size,
                              hipStream_t stream) {
    const float* x0  = (const float*)d_in[0];
    const int*   eix = (const int*)d_in[1];
    const float* ew  = (const float*)d_in[2];
    const float* W1  = (const float*)d_in[3];
    const float* b1  = (const float*)d_in[4];
    const float* W2  = (const float*)d_in[5];
    const float* b2  = (const float*)d_in[6];
    const float* W3  = (const float*)d_in[7];
    const float* b3  = (const float*)d_in[8];
    const float* ipw = (const float*)d_in[9];
    const float* ipb = (const float*)d_in[10];
    const float* opw = (const float*)d_in[11];
    const float* opb = (const float*)d_in[12];
    float* out = (float*)d_out;

    char* ws = (char*)d_ws;
    size_t o = 0;
    auto alloc = [&](size_t bytes) -> void* {
        void* p = ws + o;
        o = (o + bytes + 255) & ~size_t(255);
        return p;
    };
    float* dinv  = (float*)alloc(N_NODES * 4);   // deg -> dinv in place
    int*   cnt   = (int*)alloc(N_NODES * 4);
    int*   off   = (int*)alloc((N_NODES + 1) * 4);
    int*   fill  = (int*)alloc(N_NODES * 4);
    unsigned long long* ep = (unsigned long long*)alloc((size_t)N_EDGES * 8);
    unsigned short* x0b  = (unsigned short*)alloc((size_t)N_NODES * 256 * 2);
    unsigned short* W1t  = (unsigned short*)alloc(256 * 256 * 2);
    unsigned short* W2t  = (unsigned short*)alloc(256 * 256 * 2);
    unsigned short* W3t  = (unsigned short*)alloc(128 * 256 * 2);
    unsigned short* ipwb = (unsigned short*)alloc(768 * 256 * 2);
    unsigned short* opwb = (unsigned short*)alloc(256 * 256 * 2);
    float* ipbs          = (float*)alloc(768 * 4);
    unsigned short* Hb   = (unsigned short*)alloc((size_t)N_NODES * 256 * 2);
    unsigned short* XAb  = (unsigned short*)alloc((size_t)N_NODES * 256 * 2);
    unsigned short* XBb  = (unsigned short*)alloc((size_t)N_NODES * 256 * 2);
    unsigned short* QKVb = (unsigned short*)alloc((size_t)N_NODES * 768 * 2);
    unsigned short* Vt   = (unsigned short*)alloc((size_t)4 * 64 * 4096 * 2);
    unsigned short* Po   = (unsigned short*)alloc((size_t)16 * 4096 * 64 * 2);
    float* Pl            = (float*)alloc((size_t)16 * 4096 * 4);

    const int* row = eix;
    const int* col = eix + N_EDGES;

    hipMemsetAsync(dinv, 0, N_NODES * 4, stream);
    hipMemsetAsync(cnt, 0, N_NODES * 4, stream);
    prep_all<<<512, 256, 0, stream>>>(x0, ipw, opw, ipb, W1, W2, W3,
                                      x0b, ipwb, opwb, ipbs, W1t, W2t, W3t);
    deg_accum<<<512, 256, 0, stream>>>(col, ew, dinv, cnt);
    scan_offsets<<<1, 1024, 0, stream>>>(cnt, dinv, off, fill);
    scatter_edges<<<512, 256, 0, stream>>>(row, col, ew, dinv, fill, ep);

    // GCN layer 1
    gemm_bf16<false, 0, false><<<dim3(4, 128), 64, 0, stream>>>(x0b, W1t, nullptr, Hb, nullptr, 256);
    gcn_agg<256, false><<<N_NODES, 64, 0, stream>>>(Hb, off, ep, dinv, b1, XAb, nullptr);
    // MHA 1 (+relu)
    gemm_bf16<true, 0, true><<<dim3(12, 128), 64, 0, stream>>>(XAb, ipwb, ipbs, QKVb, Vt, 768);
    attn_mfma<<<1024, 256, 0, stream>>>(QKVb, Vt, Po, Pl);
    attn_combine<<<N_NODES / 4, 256, 0, stream>>>(Po, Pl, Hb);
    gemm_bf16<true, 1, false><<<dim3(4, 128), 64, 0, stream>>>(Hb, opwb, opb, XBb, nullptr, 256);
    // GCN layer 2
    gemm_bf16<false, 0, false><<<dim3(4, 128), 64, 0, stream>>>(XBb, W2t, nullptr, Hb, nullptr, 256);
    gcn_agg<256, false><<<N_NODES, 64, 0, stream>>>(Hb, off, ep, dinv, b2, XAb, nullptr);
    // MHA 2 (+relu)
    gemm_bf16<true, 0, true><<<dim3(12, 128), 64, 0, stream>>>(XAb, ipwb, ipbs, QKVb, Vt, 768);
    attn_mfma<<<1024, 256, 0, stream>>>(QKVb, Vt, Po, Pl);
    attn_combine<<<N_NODES / 4, 256, 0, stream>>>(Po, Pl, Hb);
    gemm_bf16<true, 1, false><<<dim3(4, 128), 64, 0, stream>>>(Hb, opwb, opb, XBb, nullptr, 256);
    // GCN layer 3 (+sigmoid) -> d_out
    gemm_bf16<false, 0, false><<<dim3(2, 128), 64, 0, stream>>>(XBb, W3t, nullptr, Hb, nullptr, 128);
    gcn_agg<128, true><<<N_NODES, 64, 0, stream>>>(Hb, off, ep, dinv, b3, nullptr, out);
}

// Round 12
// 301.297 us; speedup vs baseline: 1.0506x; 1.0052x over previous
//
#include <hip/hip_runtime.h>
#include <math.h>

#define N_NODES 4096
#define N_EDGES 262144

typedef __attribute__((ext_vector_type(4))) float f32x4;
typedef __attribute__((ext_vector_type(8))) short s16x8;
typedef __attribute__((ext_vector_type(4))) unsigned short u16x4;

__device__ inline unsigned short f2bf(float f) {
    unsigned u = __builtin_bit_cast(unsigned, f);
    u += 0x7FFF + ((u >> 16) & 1);  // RNE
    return (unsigned short)(u >> 16);
}
__device__ inline unsigned short f2bf_t(float f) {  // truncate (1 op)
    return (unsigned short)(__builtin_bit_cast(unsigned, f) >> 16);
}
__device__ inline float bf2f(unsigned short u) {
    unsigned x = ((unsigned)u) << 16;
    return __builtin_bit_cast(float, x);
}

// T2 XOR swizzle for 128-byte LDS rows
#define SWZ(row, colb) (((row) << 7) + ((colb) ^ (((row) & 7) << 4)))

// ---------------------------------------------------------------------------
// Fused prep: x0->bf16, ipw(+K scale)->bf16, opw->bf16, W1/W2/W3 T->bf16, ipb,
// plus deg/cnt zeroing (replaces two hipMemsetAsync dispatches).
// ---------------------------------------------------------------------------
__global__ void prep_all(const float* __restrict__ x0, const float* __restrict__ ipw,
                         const float* __restrict__ opw, const float* __restrict__ ipb,
                         const float* __restrict__ W1, const float* __restrict__ W2,
                         const float* __restrict__ W3,
                         unsigned short* __restrict__ x0b, unsigned short* __restrict__ ipwb,
                         unsigned short* __restrict__ opwb, float* __restrict__ ipbs,
                         unsigned short* __restrict__ W1t, unsigned short* __restrict__ W2t,
                         unsigned short* __restrict__ W3t,
                         float* __restrict__ deg, int* __restrict__ cnt) {
    const int NA = 262144;   // x0 vec4
    const int NB = 49152;    // ipw vec4
    const int NC = 16384;    // opw vec4
    const int ND1 = 65536, ND2 = 65536, ND3 = 32768;  // transposes (scalar)
    const int NE = 768;
    const int NF = 4096;     // deg/cnt zero
    const int total = NA + NB + NC + ND1 + ND2 + ND3 + NE + NF;
    for (int idx = blockIdx.x * blockDim.x + threadIdx.x; idx < total;
         idx += gridDim.x * blockDim.x) {
        int t = idx;
        if (t < NA) {
            int i = t * 4;
            f32x4 v = *(const f32x4*)(x0 + i);
            u16x4 o;
#pragma unroll
            for (int j = 0; j < 4; j++) o[j] = f2bf(v[j]);
            *(u16x4*)(x0b + i) = o;
            continue;
        }
        t -= NA;
        if (t < NB) {
            int i = t * 4;
            int r = i >> 8;
            float sc = (r >= 256 && r < 512) ? 0.1803369f : 1.0f;  // 0.125*log2(e)
            f32x4 v = *(const f32x4*)(ipw + i);
            u16x4 o;
#pragma unroll
            for (int j = 0; j < 4; j++) o[j] = f2bf(v[j] * sc);
            *(u16x4*)(ipwb + i) = o;
            continue;
        }
        t -= NB;
        if (t < NC) {
            int i = t * 4;
            f32x4 v = *(const f32x4*)(opw + i);
            u16x4 o;
#pragma unroll
            for (int j = 0; j < 4; j++) o[j] = f2bf(v[j]);
            *(u16x4*)(opwb + i) = o;
            continue;
        }
        t -= NC;
        if (t < ND1) {
            int r = t & 255, c = t >> 8;
            W1t[c * 256 + r] = f2bf(W1[r * 256 + c]);
            continue;
        }
        t -= ND1;
        if (t < ND2) {
            int r = t & 255, c = t >> 8;
            W2t[c * 256 + r] = f2bf(W2[r * 256 + c]);
            continue;
        }
        t -= ND2;
        if (t < ND3) {
            int r = t & 255, c = t >> 8;   // c in 0..127
            W3t[c * 256 + r] = f2bf(W3[r * 128 + c]);
            continue;
        }
        t -= ND3;
        if (t < NE) {
            float sc = (t >= 256 && t < 512) ? 0.1803369f : 1.0f;
            ipbs[t] = ipb[t] * sc;
            continue;
        }
        t -= NE;
        deg[t] = 0.f;
        cnt[t] = 0;
    }
}

// ---------------------------------------------------------------------------
// Graph preprocessing
// ---------------------------------------------------------------------------
__global__ void deg_accum(const int* __restrict__ col, const float* __restrict__ ew,
                          float* deg, int* cnt) {
    for (int e = blockIdx.x * blockDim.x + threadIdx.x; e < N_EDGES;
         e += gridDim.x * blockDim.x) {
        int c = col[e];
        atomicAdd(&deg[c], ew[e]);
        atomicAdd(&cnt[c], 1);
    }
}

// dinv = rsqrt(deg + 1) + exclusive scan of cnt
__global__ __launch_bounds__(1024) void scan_offsets(const int* __restrict__ cnt,
                                                     float* __restrict__ deg,
                                                     int* off, int* fill) {
    __shared__ int s[1024];
    int tid = threadIdx.x;
#pragma unroll
    for (int q = 0; q < 4; q++) {
        int i = tid * 4 + q;
        deg[i] = rsqrtf(deg[i] + 1.0f);
    }
    int c0 = cnt[tid * 4 + 0], c1 = cnt[tid * 4 + 1];
    int c2 = cnt[tid * 4 + 2], c3 = cnt[tid * 4 + 3];
    int lsum = c0 + c1 + c2 + c3;
    s[tid] = lsum;
    __syncthreads();
    for (int d = 1; d < 1024; d <<= 1) {
        int v = (tid >= d) ? s[tid - d] : 0;
        __syncthreads();
        s[tid] += v;
        __syncthreads();
    }
    int incl = s[tid];
    int base = incl - lsum;
    int o0 = base, o1 = base + c0, o2 = base + c0 + c1, o3 = base + c0 + c1 + c2;
    off[tid * 4 + 0] = o0;  fill[tid * 4 + 0] = o0;
    off[tid * 4 + 1] = o1;  fill[tid * 4 + 1] = o1;
    off[tid * 4 + 2] = o2;  fill[tid * 4 + 2] = o2;
    off[tid * 4 + 3] = o3;  fill[tid * 4 + 3] = o3;
    if (tid == 1023) off[4096] = incl;
}

// pack {row, norm} into one u64 per edge
__global__ void scatter_edges(const int* __restrict__ row, const int* __restrict__ col,
                              const float* __restrict__ ew, const float* __restrict__ dinv,
                              int* fill, unsigned long long* __restrict__ ep) {
    for (int e = blockIdx.x * blockDim.x + threadIdx.x; e < N_EDGES;
         e += gridDim.x * blockDim.x) {
        int r = row[e], c = col[e];
        int p = atomicAdd(&fill[c], 1);
        float w = dinv[r] * ew[e] * dinv[c];
        unsigned long long v =
            ((unsigned long long)__builtin_bit_cast(unsigned, w) << 32) | (unsigned)r;
        ep[p] = v;
    }
}

// ---------------------------------------------------------------------------
// Single-wave bf16 GEMM: 32x64 tile/wave. C = A[N][256] @ B^T (B [P][256] bf16)
// QKV=true: bcol>=512 blocks write transposed Vt [head][d][n] directly.
// grid (P/64, N/32), 64 threads.
// ---------------------------------------------------------------------------
template <bool BIAS, int ACT, bool QKV>
__global__ __launch_bounds__(64) void gemm_bf16(const unsigned short* __restrict__ A,
                                                const unsigned short* __restrict__ B,
                                                const float* __restrict__ bias,
                                                unsigned short* __restrict__ C,
                                                unsigned short* __restrict__ Vt, int P) {
    int lane = threadIdx.x & 63;
    int lx = lane & 15, g = lane >> 4;
    int brow = blockIdx.y * 32, bcol = blockIdx.x * 64;
    const unsigned short* Ap0 = A + (size_t)(brow + lx) * 256 + g * 8;
    const unsigned short* Ap1 = Ap0 + 16 * 256;
    const unsigned short* Bp = B + (size_t)(bcol + lx) * 256 + g * 8;
    f32x4 acc[2][4];
#pragma unroll
    for (int mi = 0; mi < 2; mi++)
#pragma unroll
        for (int nt = 0; nt < 4; nt++) acc[mi][nt] = f32x4{0.f, 0.f, 0.f, 0.f};
#pragma unroll
    for (int kc = 0; kc < 8; kc++) {
        s16x8 a0 = *(const s16x8*)(Ap0 + kc * 32);
        s16x8 a1 = *(const s16x8*)(Ap1 + kc * 32);
#pragma unroll
        for (int nt = 0; nt < 4; nt++) {
            s16x8 b = *(const s16x8*)(Bp + (size_t)nt * 16 * 256 + kc * 32);
            acc[0][nt] = __builtin_amdgcn_mfma_f32_16x16x32_bf16(a0, b, acc[0][nt], 0, 0, 0);
            acc[1][nt] = __builtin_amdgcn_mfma_f32_16x16x32_bf16(a1, b, acc[1][nt], 0, 0, 0);
        }
    }
    bool isV = QKV && (bcol >= 512);
    if (!isV) {
#pragma unroll
        for (int mi = 0; mi < 2; mi++)
#pragma unroll
            for (int nt = 0; nt < 4; nt++)
#pragma unroll
                for (int r = 0; r < 4; r++) {
                    int row = brow + mi * 16 + g * 4 + r, col = bcol + nt * 16 + lx;
                    float v = acc[mi][nt][r];
                    if (BIAS) v += bias[col];
                    if (ACT == 1) v = fmaxf(v, 0.f);
                    C[(size_t)row * P + col] = f2bf(v);
                }
    } else {
        int head = (bcol - 512) >> 6;
#pragma unroll
        for (int mi = 0; mi < 2; mi++)
#pragma unroll
            for (int nt = 0; nt < 4; nt++) {
                int col = bcol + nt * 16 + lx;
                u16x4 vv;
#pragma unroll
                for (int r = 0; r < 4; r++) {
                    float v = acc[mi][nt][r];
                    if (BIAS) v += bias[col];
                    vv[r] = f2bf(v);
                }
                *(u16x4*)(Vt + (size_t)(head * 64 + nt * 16 + lx) * 4096 +
                          brow + mi * 16 + g * 4) = vv;
            }
    }
}

// ---------------------------------------------------------------------------
// Out-proj GEMM with FUSED attention combine: A[row][k] is computed on the fly
// as (sum_c Po[c,h,row,d]) * Linv[h,row], h=k>>6, d=k&63.
// C = relu(A @ opw^T + opb), 32x64 tile/wave, grid (4, 128), 64 threads.
// ---------------------------------------------------------------------------
__global__ __launch_bounds__(64) void gemm_op(const unsigned short* __restrict__ Po,
                                              const float* __restrict__ Pl,
                                              const unsigned short* __restrict__ B,
                                              const float* __restrict__ bias,
                                              unsigned short* __restrict__ C) {
    int lane = threadIdx.x & 63;
    int lx = lane & 15, g = lane >> 4;
    int brow = blockIdx.y * 32, bcol = blockIdx.x * 64;
    int rows[2] = {brow + lx, brow + 16 + lx};
    // per-row, per-head inverse softmax denominators
    float Linv[2][4];
#pragma unroll
    for (int mi = 0; mi < 2; mi++)
#pragma unroll
        for (int h = 0; h < 4; h++) {
            float L = 0.f;
#pragma unroll
            for (int c = 0; c < 4; c++)
                L += Pl[(size_t)(c * 4 + h) * 4096 + rows[mi]];
            Linv[mi][h] = 1.0f / L;
        }
    const unsigned short* Bp = B + (size_t)(bcol + lx) * 256 + g * 8;
    f32x4 acc[2][4];
#pragma unroll
    for (int mi = 0; mi < 2; mi++)
#pragma unroll
        for (int nt = 0; nt < 4; nt++) acc[mi][nt] = f32x4{0.f, 0.f, 0.f, 0.f};
#pragma unroll
    for (int kc = 0; kc < 8; kc++) {
        int k0 = kc * 32 + g * 8;
        int h = k0 >> 6, d0 = k0 & 63;
        s16x8 a[2];
#pragma unroll
        for (int mi = 0; mi < 2; mi++) {
            float sum[8] = {0.f, 0.f, 0.f, 0.f, 0.f, 0.f, 0.f, 0.f};
#pragma unroll
            for (int c = 0; c < 4; c++) {
                s16x8 p = *(const s16x8*)(Po +
                    ((size_t)(c * 4 + h) * 4096 + rows[mi]) * 64 + d0);
#pragma unroll
                for (int j = 0; j < 8; j++) sum[j] += bf2f((unsigned short)p[j]);
            }
            s16x8 av;
            float li = Linv[mi][h];
#pragma unroll
            for (int j = 0; j < 8; j++) av[j] = (short)f2bf(sum[j] * li);
            a[mi] = av;
        }
#pragma unroll
        for (int nt = 0; nt < 4; nt++) {
            s16x8 b = *(const s16x8*)(Bp + (size_t)nt * 16 * 256 + kc * 32);
            acc[0][nt] = __builtin_amdgcn_mfma_f32_16x16x32_bf16(a[0], b, acc[0][nt], 0, 0, 0);
            acc[1][nt] = __builtin_amdgcn_mfma_f32_16x16x32_bf16(a[1], b, acc[1][nt], 0, 0, 0);
        }
    }
#pragma unroll
    for (int mi = 0; mi < 2; mi++)
#pragma unroll
        for (int nt = 0; nt < 4; nt++)
#pragma unroll
            for (int r = 0; r < 4; r++) {
                int row = brow + mi * 16 + g * 4 + r, col = bcol + nt * 16 + lx;
                float v = fmaxf(acc[mi][nt][r] + bias[col], 0.f);
                C[(size_t)row * 256 + col] = f2bf(v);
            }
}

// ---------------------------------------------------------------------------
// GCN aggregation: 1 wave per node, packed edge metadata, 128-edge LDS stages
// ---------------------------------------------------------------------------
template <int P, bool SIG>
__global__ __launch_bounds__(64) void gcn_agg(const unsigned short* __restrict__ H,
                                              const int* __restrict__ off,
                                              const unsigned long long* __restrict__ ep,
                                              const float* __restrict__ dinv,
                                              const float* __restrict__ bias,
                                              unsigned short* __restrict__ outb,
                                              float* __restrict__ outf) {
    constexpr int CPT = P / 64;  // cols per thread (4 or 2)
    __shared__ unsigned long long se[128];
    int i = blockIdx.x, tid = threadIdx.x;
    float di = dinv[i];
    float d2 = di * di;
    float acc[CPT];
    if (CPT == 4) {
        u16x4 h = *(const u16x4*)(H + (size_t)i * P + tid * 4);
#pragma unroll
        for (int j = 0; j < 4; j++) acc[j] = d2 * bf2f(h[j]);
    } else {
        unsigned h = *(const unsigned*)(H + (size_t)i * P + tid * 2);
        acc[0] = d2 * bf2f((unsigned short)(h & 0xFFFF));
        acc[1] = d2 * bf2f((unsigned short)(h >> 16));
    }
    int beg = off[i], end = off[i + 1];
    for (int base = beg; base < end; base += 128) {
        int n = min(128, end - base);
        __syncthreads();
        if (tid < n) se[tid] = ep[base + tid];
        if (tid + 64 < n) se[tid + 64] = ep[base + tid + 64];
        __syncthreads();
#pragma unroll 4
        for (int j = 0; j < n; j++) {
            unsigned long long v = se[j];
            int r = (int)(unsigned)v;
            float w = __builtin_bit_cast(float, (unsigned)(v >> 32));
            size_t rb = (size_t)r * P;
            if (CPT == 4) {
                u16x4 h = *(const u16x4*)(H + rb + tid * 4);
#pragma unroll
                for (int q = 0; q < 4; q++) acc[q] += w * bf2f(h[q]);
            } else {
                unsigned h = *(const unsigned*)(H + rb + tid * 2);
                acc[0] += w * bf2f((unsigned short)(h & 0xFFFF));
                acc[1] += w * bf2f((unsigned short)(h >> 16));
            }
        }
    }
#pragma unroll
    for (int j = 0; j < CPT; j++) {
        int c = tid * CPT + j;
        float v = acc[j] + bias[c];
        if (SIG) {
            v = 1.f / (1.f + exp2f(-v * 1.442695f));
            outf[(size_t)i * P + c] = v;
        } else {
            outb[(size_t)i * P + c] = f2bf(v);
        }
    }
}

// ---------------------------------------------------------------------------
// MFMA flash attention: fixed-base exp2 softmax, double-buffered K/V (1-deep
// staging), XCD-pinned (head,chunk) block decode. grid 1024 1D, 256 threads.
// ---------------------------------------------------------------------------
__global__ __launch_bounds__(256) void attn_mfma(const unsigned short* __restrict__ qkv,
                                                 const unsigned short* __restrict__ Vt,
                                                 unsigned short* __restrict__ Po,
                                                 float* __restrict__ Pl) {
    __shared__ unsigned short Ks[2][64 * 64];
    __shared__ unsigned short Vs[2][64 * 64];
    __shared__ unsigned short Ps[4][16 * 64];

    int tid = threadIdx.x;
    int wid = tid >> 6, lane = tid & 63, g = lane >> 4, lx = lane & 15;
    // XCD-pinned decode: each XCD owns 2 (head,chunk) pairs x 64 q-tiles
    int bid = blockIdx.x;
    int xcd = bid & 7, loc = bid >> 3;
    int pair = xcd * 2 + (loc >> 6);
    int qt = loc & 63;
    int head = pair >> 2, chunk = pair & 3;
    int qw = qt * 64 + wid * 16;

    s16x8 qa[2];
#pragma unroll
    for (int kc = 0; kc < 2; kc++)
        qa[kc] = *(const s16x8*)(qkv + (size_t)(qw + lx) * 768 + head * 64 + kc * 32 + g * 8);

    int kr0 = tid >> 3, dc0 = tid & 7;
    int kr1 = kr0 + 32;
    int kt_beg = chunk * 16, kt_end = kt_beg + 16;

    const unsigned short* kp0 =
        qkv + 256 + head * 64 + (size_t)(kt_beg * 64 + kr0) * 768 + dc0 * 8;
    const unsigned short* kp1 = kp0 + (size_t)32 * 768;
    const unsigned short* vp0 =
        Vt + (size_t)head * 64 * 4096 + (size_t)kr0 * 4096 + kt_beg * 64 + dc0 * 8;
    const unsigned short* vp1 = vp0 + (size_t)32 * 4096;

    s16x8 stK[2], stV[2];
    auto issue = [&]() {
        stK[0] = *(const s16x8*)kp0;
        stK[1] = *(const s16x8*)kp1;
        stV[0] = *(const s16x8*)vp0;
        stV[1] = *(const s16x8*)vp1;
        kp0 += (size_t)64 * 768; kp1 += (size_t)64 * 768;
        vp0 += 64; vp1 += 64;
    };
    auto commit = [&](int b) {
        *(s16x8*)((char*)Ks[b] + SWZ(kr0, dc0 * 16)) = stK[0];
        *(s16x8*)((char*)Ks[b] + SWZ(kr1, dc0 * 16)) = stK[1];
        *(s16x8*)((char*)Vs[b] + SWZ(kr0, dc0 * 16)) = stV[0];
        *(s16x8*)((char*)Vs[b] + SWZ(kr1, dc0 * 16)) = stV[1];
    };

    float lreg[4] = {0.f, 0.f, 0.f, 0.f};
    f32x4 o[4];
#pragma unroll
    for (int dt = 0; dt < 4; dt++) o[dt] = f32x4{0.f, 0.f, 0.f, 0.f};

    char* PsW = (char*)Ps[wid];

    issue();
    commit(0);
    __syncthreads();

    for (int kt = kt_beg; kt < kt_end; kt++) {
        int cur = (kt - kt_beg) & 1;
        if (kt + 1 < kt_end) issue();

        f32x4 s4[4];
        __builtin_amdgcn_s_setprio(1);
#pragma unroll
        for (int nt = 0; nt < 4; nt++) {
            f32x4 acc = f32x4{0.f, 0.f, 0.f, 0.f};
#pragma unroll
            for (int kc = 0; kc < 2; kc++) {
                s16x8 kb = *(const s16x8*)((char*)Ks[cur] + SWZ(nt * 16 + lx, kc * 64 + g * 16));
                acc = __builtin_amdgcn_mfma_f32_16x16x32_bf16(qa[kc], kb, acc, 0, 0, 0);
            }
            s4[nt] = acc;
        }
        __builtin_amdgcn_s_setprio(0);

        // fixed-base softmax: P = exp2(min(s,60)); per-lane l accumulation
#pragma unroll
        for (int nt = 0; nt < 4; nt++)
#pragma unroll
            for (int r = 0; r < 4; r++) {
                float p = exp2f(fminf(s4[nt][r], 60.f));
                lreg[r] += p;
                *(unsigned short*)(PsW + SWZ(4 * g + r, (nt * 16 + lx) * 2)) = f2bf_t(p);
            }

        __builtin_amdgcn_s_setprio(1);
#pragma unroll
        for (int kc = 0; kc < 2; kc++) {
            s16x8 pa = *(const s16x8*)(PsW + SWZ(lx, kc * 64 + g * 16));
#pragma unroll
            for (int dt = 0; dt < 4; dt++) {
                s16x8 vb = *(const s16x8*)((char*)Vs[cur] + SWZ(dt * 16 + lx, kc * 64 + g * 16));
                o[dt] = __builtin_amdgcn_mfma_f32_16x16x32_bf16(pa, vb, o[dt], 0, 0, 0);
            }
        }
        __builtin_amdgcn_s_setprio(0);

        if (kt + 1 < kt_end) commit(1 - cur);
        __syncthreads();
    }

#pragma unroll
    for (int r = 0; r < 4; r++) {
        float ls = lreg[r];
        ls += __shfl_xor(ls, 1, 16);
        ls += __shfl_xor(ls, 2, 16);
        ls += __shfl_xor(ls, 4, 16);
        ls += __shfl_xor(ls, 8, 16);
        int qrow = qw + 4 * g + r;
        size_t base = (size_t)(chunk * 4 + head) * 4096 + qrow;
        if (lx == 0) Pl[base] = ls;
#pragma unroll
        for (int dt = 0; dt < 4; dt++)
            Po[base * 64 + dt * 16 + lx] = f2bf(o[dt][r]);
    }
}

// ---------------------------------------------------------------------------
extern "C" void kernel_launch(void* const* d_in, const int* in_sizes, int n_in,
                              void* d_out, int out_size, void* d_ws, size_t ws_size,
                              hipStream_t stream) {
    const float* x0  = (const float*)d_in[0];
    const int*   eix = (const int*)d_in[1];
    const float* ew  = (const float*)d_in[2];
    const float* W1  = (const float*)d_in[3];
    const float* b1  = (const float*)d_in[4];
    const float* W2  = (const float*)d_in[5];
    const float* b2  = (const float*)d_in[6];
    const float* W3  = (const float*)d_in[7];
    const float* b3  = (const float*)d_in[8];
    const float* ipw = (const float*)d_in[9];
    const float* ipb = (const float*)d_in[10];
    const float* opw = (const float*)d_in[11];
    const float* opb = (const float*)d_in[12];
    float* out = (float*)d_out;

    char* ws = (char*)d_ws;
    size_t o = 0;
    auto alloc = [&](size_t bytes) -> void* {
        void* p = ws + o;
        o = (o + bytes + 255) & ~size_t(255);
        return p;
    };
    float* dinv  = (float*)alloc(N_NODES * 4);   // deg -> dinv in place
    int*   cnt   = (int*)alloc(N_NODES * 4);
    int*   off   = (int*)alloc((N_NODES + 1) * 4);
    int*   fill  = (int*)alloc(N_NODES * 4);
    unsigned long long* ep = (unsigned long long*)alloc((size_t)N_EDGES * 8);
    unsigned short* x0b  = (unsigned short*)alloc((size_t)N_NODES * 256 * 2);
    unsigned short* W1t  = (unsigned short*)alloc(256 * 256 * 2);
    unsigned short* W2t  = (unsigned short*)alloc(256 * 256 * 2);
    unsigned short* W3t  = (unsigned short*)alloc(128 * 256 * 2);
    unsigned short* ipwb = (unsigned short*)alloc(768 * 256 * 2);
    unsigned short* opwb = (unsigned short*)alloc(256 * 256 * 2);
    float* ipbs          = (float*)alloc(768 * 4);
    unsigned short* Hb   = (unsigned short*)alloc((size_t)N_NODES * 256 * 2);
    unsigned short* XAb  = (unsigned short*)alloc((size_t)N_NODES * 256 * 2);
    unsigned short* XBb  = (unsigned short*)alloc((size_t)N_NODES * 256 * 2);
    unsigned short* QKVb = (unsigned short*)alloc((size_t)N_NODES * 768 * 2);
    unsigned short* Vt   = (unsigned short*)alloc((size_t)4 * 64 * 4096 * 2);
    unsigned short* Po   = (unsigned short*)alloc((size_t)16 * 4096 * 64 * 2);
    float* Pl            = (float*)alloc((size_t)16 * 4096 * 4);

    const int* row = eix;
    const int* col = eix + N_EDGES;

    prep_all<<<512, 256, 0, stream>>>(x0, ipw, opw, ipb, W1, W2, W3,
                                      x0b, ipwb, opwb, ipbs, W1t, W2t, W3t, dinv, cnt);
    deg_accum<<<512, 256, 0, stream>>>(col, ew, dinv, cnt);
    scan_offsets<<<1, 1024, 0, stream>>>(cnt, dinv, off, fill);
    scatter_edges<<<512, 256, 0, stream>>>(row, col, ew, dinv, fill, ep);

    // GCN layer 1
    gemm_bf16<false, 0, false><<<dim3(4, 128), 64, 0, stream>>>(x0b, W1t, nullptr, Hb, nullptr, 256);
    gcn_agg<256, false><<<N_NODES, 64, 0, stream>>>(Hb, off, ep, dinv, b1, XAb, nullptr);
    // MHA 1 (+relu), combine fused into out-proj
    gemm_bf16<true, 0, true><<<dim3(12, 128), 64, 0, stream>>>(XAb, ipwb, ipbs, QKVb, Vt, 768);
    attn_mfma<<<1024, 256, 0, stream>>>(QKVb, Vt, Po, Pl);
    gemm_op<<<dim3(4, 128), 64, 0, stream>>>(Po, Pl, opwb, opb, XBb);
    // GCN layer 2
    gemm_bf16<false, 0, false><<<dim3(4, 128), 64, 0, stream>>>(XBb, W2t, nullptr, Hb, nullptr, 256);
    gcn_agg<256, false><<<N_NODES, 64, 0, stream>>>(Hb, off, ep, dinv, b2, XAb, nullptr);
    // MHA 2 (+relu)
    gemm_bf16<true, 0, true><<<dim3(12, 128), 64, 0, stream>>>(XAb, ipwb, ipbs, QKVb, Vt, 768);
    attn_mfma<<<1024, 256, 0, stream>>>(QKVb, Vt, Po, Pl);
    gemm_op<<<dim3(4, 128), 64, 0, stream>>>(Po, Pl, opwb, opb, XBb);
    // GCN layer 3 (+sigmoid) -> d_out
    gemm_bf16<false, 0, false><<<dim3(2, 128), 64, 0, stream>>>(XBb, W3t, nullptr, Hb, nullptr, 128);
    gcn_agg<128, true><<<N_NODES, 64, 0, stream>>>(Hb, off, ep, dinv, b3, nullptr, out);
}